// Round 3
// baseline (206.326 us; speedup 1.0000x reference)
//
#include <hip/hip_runtime.h>
#include <stdint.h>

#define DIM 1024
#define GLOBAL_AS __attribute__((address_space(1)))
#define LDS_AS __attribute__((address_space(3)))

typedef short bf16x8 __attribute__((ext_vector_type(8)));
typedef float f32x4 __attribute__((ext_vector_type(4)));

// Taylor 1/k! coefficients for Paterson-Stockmeyer deg-6
#define C3 0.16666667f
#define C4 0.041666668f
#define C5 0.008333334f
#define C6 0.0013888889f

__device__ __forceinline__ unsigned short f32_to_bf16(float f) {
    union { float f; uint32_t u; } v; v.f = f;
    uint32_t u = v.u;
    u += 0x7FFFu + ((u >> 16) & 1u);   // round-to-nearest-even
    return (unsigned short)(u >> 16);
}
__device__ __forceinline__ float bf16_to_f32(unsigned short u) {
    union { uint32_t u; float f; } v; v.u = ((uint32_t)u) << 16;
    return v.f;
}

// async global->LDS, 16B per lane; LDS dst = wave-uniform base + lane*16.
__device__ __forceinline__ void async16(const void* g, void* l) {
    __builtin_amdgcn_global_load_lds((GLOBAL_AS const void*)g,
                                     (LDS_AS void*)l, 16, 0, 0);
}

// A = W - W^T; Ab = bf16(A) (A-operand), G = bf16(-A) = bf16(A^T) (B-operand).
__global__ __launch_bounds__(256) void k_init(const float* __restrict__ W,
        unsigned short* __restrict__ Ab, unsigned short* __restrict__ G) {
    int idx = blockIdx.x * 256 + threadIdx.x;
    int i = idx >> 10, j = idx & 1023;
    float a = W[i * DIM + j] - W[j * DIM + i];
    Ab[idx] = f32_to_bf16(a);
    G[idx]  = f32_to_bf16(-a);
}

// 1024^3 GEMM: acc = P * Q (Q given transposed row-major as Qt).
// 512 threads = 2 wave-groups; group g computes K in [g*512, g*512+512), BK=128.
// Partials reduced through LDS at the end. XOR-swizzled chunks, async staging.
// MODE 1: out1 = bf16(acc)                         (A2)
// MODE 2: out1 = bf16(acc) (A3);  out2 = bf16(C3*I - C4*A + C5*A2 - C6*acc) (Q^T)
// MODE 3: v = acc + I + A + 0.5*A2; LDS-transpose; out1 = bf16(v^T) (R^T)
template<int MODE>
__global__ __launch_bounds__(512) void k_pgemm(
        const unsigned short* __restrict__ P,
        const unsigned short* __restrict__ Qt,
        const unsigned short* __restrict__ Ab,
        const unsigned short* __restrict__ A2b,
        unsigned short* __restrict__ out1,
        unsigned short* __restrict__ out2) {
    __shared__ unsigned short lP[2][64 * 128];   // 32 KB
    __shared__ unsigned short lQ[2][64 * 128];   // 32 KB
    int tid = threadIdx.x;
    int m0 = blockIdx.y * 64, n0 = blockIdx.x * 64;
    int g = tid >> 8;                 // K-group (wave-uniform)
    int tg = tid & 255;
    int lane = tid & 63;
    int w4 = (tid >> 6) & 3;
    int wr = w4 >> 1, wc = w4 & 1;
    int rr = lane & 15, ko = lane >> 4;
    f32x4 acc[2][2] = {};
    int kbase = g * 512;
    for (int ks = 0; ks < 4; ks++) {
        int kb = kbase + ks * 128;
        #pragma unroll
        for (int i = 0; i < 4; i++) {
            int l = i * 256 + tg;
            int r = l >> 4, cst = l & 15;
            int cd = cst ^ (r & 7);
            async16(&P[(m0 + r) * DIM + kb + cd * 8], &lP[g][l * 8]);
            async16(&Qt[(n0 + r) * DIM + kb + cd * 8], &lQ[g][l * 8]);
        }
        __syncthreads();
        #pragma unroll
        for (int s = 0; s < 4; s++) {
            int cd = s * 4 + ko;
            bf16x8 af[2], bq[2];
            #pragma unroll
            for (int mi = 0; mi < 2; mi++) {
                int ra = wr * 32 + mi * 16 + rr;
                af[mi] = *(const bf16x8*)&lP[g][ra * 128 + ((cd ^ (ra & 7)) * 8)];
            }
            #pragma unroll
            for (int ni = 0; ni < 2; ni++) {
                int rb = wc * 32 + ni * 16 + rr;
                bq[ni] = *(const bf16x8*)&lQ[g][rb * 128 + ((cd ^ (rb & 7)) * 8)];
            }
            #pragma unroll
            for (int mi = 0; mi < 2; mi++)
                #pragma unroll
                for (int ni = 0; ni < 2; ni++)
                    acc[mi][ni] = __builtin_amdgcn_mfma_f32_16x16x32_bf16(
                        af[mi], bq[ni], acc[mi][ni], 0, 0, 0);
        }
        __syncthreads();
    }
    // cross-group reduction: group 1 dumps partials, group 0 adds.
    float* rb = (float*)&lP[0][0];    // 16 KB
    if (g == 1) {
        #pragma unroll
        for (int mi = 0; mi < 2; mi++)
            #pragma unroll
            for (int ni = 0; ni < 2; ni++)
                *(f32x4*)&rb[(w4 * 64 + lane) * 16 + (mi * 2 + ni) * 4] = acc[mi][ni];
    }
    __syncthreads();
    if (g == 0) {
        #pragma unroll
        for (int mi = 0; mi < 2; mi++)
            #pragma unroll
            for (int ni = 0; ni < 2; ni++)
                acc[mi][ni] += *(const f32x4*)&rb[(w4 * 64 + lane) * 16 + (mi * 2 + ni) * 4];
        if (MODE == 1 || MODE == 2) {
            #pragma unroll
            for (int mi = 0; mi < 2; mi++)
                #pragma unroll
                for (int ni = 0; ni < 2; ni++)
                    #pragma unroll
                    for (int q = 0; q < 4; q++) {
                        int rl = wr * 32 + mi * 16 + ko * 4 + q;
                        int cl = wc * 32 + ni * 16 + rr;
                        int gi = (m0 + rl) * DIM + n0 + cl;
                        float v = acc[mi][ni][q];
                        out1[gi] = f32_to_bf16(v);
                        if (MODE == 2) {
                            float a = bf16_to_f32(Ab[gi]);
                            float a2 = bf16_to_f32(A2b[gi]);
                            float d = (m0 + rl == n0 + cl) ? C3 : 0.0f;
                            out2[gi] = f32_to_bf16(d - C4 * a + C5 * a2 - C6 * v);
                        }
                    }
        } else {
            float* tb = (float*)&lQ[0][0];   // 64*65*4 = 16.6 KB
            #pragma unroll
            for (int mi = 0; mi < 2; mi++)
                #pragma unroll
                for (int ni = 0; ni < 2; ni++)
                    #pragma unroll
                    for (int q = 0; q < 4; q++) {
                        int rl = wr * 32 + mi * 16 + ko * 4 + q;
                        int cl = wc * 32 + ni * 16 + rr;
                        int gi = (m0 + rl) * DIM + n0 + cl;
                        float a = bf16_to_f32(Ab[gi]);
                        float a2 = bf16_to_f32(A2b[gi]);
                        float d = (m0 + rl == n0 + cl) ? 1.0f : 0.0f;
                        tb[cl * 65 + rl] = acc[mi][ni][q] + d + a + 0.5f * a2;
                    }
        }
    }
    if (MODE == 3) {
        __syncthreads();
        if (g == 0) {
            const float* tb = (const float*)&lQ[0][0];
            #pragma unroll
            for (int q = 0; q < 16; q++) {
                int l = tg * 16 + q;
                int orow = l >> 6, ocol = l & 63;
                out1[(n0 + orow) * DIM + m0 + ocol] = f32_to_bf16(tb[orow * 65 + ocol]);
            }
        }
    }
}

// Out(16384x1024) = X(fp32, converted in-flight) @ R, R^T row-major bf16 (Rtb).
// 128x128 tiles, grid 1024 = 4 blocks/CU. bid mapping: m = bid&127 so all 8
// n-tiles of an m-strip share an XCD (X tile served from that XCD's L2).
// X staged fp32 via global_load_lds; converted to bf16 at fragment read with
// +0x8000 bias (round-half-up) and v_perm packing.
__global__ __launch_bounds__(256) void k_biggemm(
        const float* __restrict__ X,
        const unsigned short* __restrict__ Rtb,
        float* __restrict__ Out) {
    __shared__ float lX[128 * 32];            // 16 KB (fp32)
    __shared__ unsigned short lB[128 * 32];   // 8 KB (bf16)
    int tid = threadIdx.x;
    int bid = blockIdx.x;
    int m0 = (bid & 127) * 128, n0 = (bid >> 7) * 128;
    int lane = tid & 63, w = tid >> 6;
    int wr = w >> 1, wc = w & 1;
    int rr = lane & 15, ko = lane >> 4;
    f32x4 acc[4][4] = {};
    for (int kb = 0; kb < DIM; kb += 32) {
        #pragma unroll
        for (int i = 0; i < 4; i++) {          // X: 128 rows x 8 chunks (16B=4 fp32)
            int l = i * 256 + tid;
            int r = l >> 3, cst = l & 7;
            int cd = cst ^ (r & 7);
            async16(&X[(size_t)(m0 + r) * DIM + kb + cd * 4], &lX[l * 4]);
        }
        #pragma unroll
        for (int i = 0; i < 2; i++) {          // B: 128 rows x 4 chunks (16B=8 bf16)
            int l = i * 256 + tid;
            int r = l >> 2, cst = l & 3;
            int cd = cst ^ ((r >> 1) & 3);
            async16(&Rtb[(n0 + r) * DIM + kb + cd * 8], &lB[l * 8]);
        }
        __syncthreads();
        bf16x8 af[4], bq[4];
        #pragma unroll
        for (int mi = 0; mi < 4; mi++) {
            int ra = wr * 64 + mi * 16 + rr;
            int s0 = (2 * ko) ^ (ra & 7);
            int s1 = (2 * ko + 1) ^ (ra & 7);
            union { f32x4 f; uint32_t u[4]; } a0, a1;
            a0.f = *(const f32x4*)&lX[ra * 32 + s0 * 4];
            a1.f = *(const f32x4*)&lX[ra * 32 + s1 * 4];
            union { uint32_t u[4]; bf16x8 v; } pk;
            uint32_t b0 = a0.u[0] + 0x8000u, b1 = a0.u[1] + 0x8000u;
            uint32_t b2 = a0.u[2] + 0x8000u, b3 = a0.u[3] + 0x8000u;
            uint32_t b4 = a1.u[0] + 0x8000u, b5 = a1.u[1] + 0x8000u;
            uint32_t b6 = a1.u[2] + 0x8000u, b7 = a1.u[3] + 0x8000u;
            pk.u[0] = __builtin_amdgcn_perm(b1, b0, 0x07060302u);
            pk.u[1] = __builtin_amdgcn_perm(b3, b2, 0x07060302u);
            pk.u[2] = __builtin_amdgcn_perm(b5, b4, 0x07060302u);
            pk.u[3] = __builtin_amdgcn_perm(b7, b6, 0x07060302u);
            af[mi] = pk.v;
        }
        #pragma unroll
        for (int ni = 0; ni < 4; ni++) {
            int rb = wc * 64 + ni * 16 + rr;
            bq[ni] = *(const bf16x8*)&lB[rb * 32 + ((ko ^ ((rb >> 1) & 3)) * 8)];
        }
        #pragma unroll
        for (int mi = 0; mi < 4; mi++)
            #pragma unroll
            for (int ni = 0; ni < 4; ni++)
                acc[mi][ni] = __builtin_amdgcn_mfma_f32_16x16x32_bf16(
                    af[mi], bq[ni], acc[mi][ni], 0, 0, 0);
        __syncthreads();
    }
    #pragma unroll
    for (int mi = 0; mi < 4; mi++)
        #pragma unroll
        for (int ni = 0; ni < 4; ni++)
            #pragma unroll
            for (int q = 0; q < 4; q++) {
                int row = m0 + wr * 64 + mi * 16 + ko * 4 + q;
                int col = n0 + wc * 64 + ni * 16 + rr;
                Out[(size_t)row * DIM + col] = acc[mi][ni][q];
            }
}

extern "C" void kernel_launch(void* const* d_in, const int* in_sizes, int n_in,
                              void* d_out, int out_size, void* d_ws, size_t ws_size,
                              hipStream_t stream) {
    const float* X = (const float*)d_in[0];        // 4*4096*1024 fp32
    const float* W = (const float*)d_in[1];        // 1024*1024 fp32
    float* Out = (float*)d_out;                    // 16384*1024 fp32
    char* ws = (char*)d_ws;
    const size_t MB = 1u << 20;
    unsigned short* Ab  = (unsigned short*)(ws + 0 * MB);
    unsigned short* G   = (unsigned short*)(ws + 2 * MB);
    unsigned short* A2b = (unsigned short*)(ws + 4 * MB);
    unsigned short* A3b = (unsigned short*)(ws + 6 * MB);
    unsigned short* Qtb = (unsigned short*)(ws + 8 * MB);
    unsigned short* Rtb = (unsigned short*)(ws + 10 * MB);

    k_init<<<4096, 256, 0, stream>>>(W, Ab, G);
    // deg-6 Paterson-Stockmeyer: R = I + A + A2/2 + A3*(C3 I + C4 A + C5 A2 + C6 A3)
    k_pgemm<1><<<dim3(16, 16), 512, 0, stream>>>(Ab, G,   Ab, nullptr, A2b, nullptr);
    k_pgemm<2><<<dim3(16, 16), 512, 0, stream>>>(Ab, A2b, Ab, A2b,     A3b, Qtb);
    k_pgemm<3><<<dim3(16, 16), 512, 0, stream>>>(A3b, Qtb, Ab, A2b,    Rtb, nullptr);
    k_biggemm<<<1024, 256, 0, stream>>>(X, Rtb, Out);
}

// Round 4
// 196.696 us; speedup vs baseline: 1.0490x; 1.0490x over previous
//
#include <hip/hip_runtime.h>
#include <stdint.h>

#define DIM 1024
#define GLOBAL_AS __attribute__((address_space(1)))
#define LDS_AS __attribute__((address_space(3)))

typedef short bf16x8 __attribute__((ext_vector_type(8)));
typedef float f32x4 __attribute__((ext_vector_type(4)));

// Taylor coefficients: R ~= I + A + A2/2 + A3/6 + A4/24 (deg-4, ok since rho(A)~0.9)
#define C3f 0.16666667f
#define C4f 0.041666668f

__device__ __forceinline__ unsigned short f32_to_bf16(float f) {
    union { float f; uint32_t u; } v; v.f = f;
    uint32_t u = v.u;
    u += 0x7FFFu + ((u >> 16) & 1u);   // round-to-nearest-even
    return (unsigned short)(u >> 16);
}
__device__ __forceinline__ float bf16_to_f32(unsigned short u) {
    union { uint32_t u; float f; } v; v.u = ((uint32_t)u) << 16;
    return v.f;
}

// async global->LDS, 16B per lane; LDS dst = wave-uniform base + lane*16.
__device__ __forceinline__ void async16(const void* g, void* l) {
    __builtin_amdgcn_global_load_lds((GLOBAL_AS const void*)g,
                                     (LDS_AS void*)l, 16, 0, 0);
}

// A = W - W^T; Ab = bf16(A) (A-operand), G = bf16(-A) = bf16(A^T) (B-operand).
__global__ __launch_bounds__(256) void k_init(const float* __restrict__ W,
        unsigned short* __restrict__ Ab, unsigned short* __restrict__ G) {
    int idx = blockIdx.x * 256 + threadIdx.x;
    int i = idx >> 10, j = idx & 1023;
    float a = W[i * DIM + j] - W[j * DIM + i];
    Ab[idx] = f32_to_bf16(a);
    G[idx]  = f32_to_bf16(-a);
}

// Fused kernel 1:
//  blocks <  1024 : GEMM1 tile (32x32, K=1024, BK=256): A2 = A*A.
//                   Epilogue: A2b = bf16(A2), Pb = bf16(C3*A + C4*A2).
//  blocks >= 1024 : X(fp32) -> Xb(bf16) conversion, 8 elems/thread.
// The convert half is HBM-BW-bound (~96 MB); GEMM1 hides underneath it.
__global__ __launch_bounds__(256) void k_g1(
        const unsigned short* __restrict__ Ab,
        const unsigned short* __restrict__ G,
        const float* __restrict__ X,
        unsigned short* __restrict__ A2b,
        unsigned short* __restrict__ Pb,
        unsigned short* __restrict__ Xb) {
    int bid = blockIdx.x;
    int tid = threadIdx.x;
    if (bid >= 1024) {                       // ---- convert path ----
        size_t id = (size_t)(bid - 1024) * 256 + tid;
        const f32x4* p = (const f32x4*)(X + id * 8);
        f32x4 v0 = p[0], v1 = p[1];
        unsigned short o[8];
        #pragma unroll
        for (int q = 0; q < 4; q++) { o[q] = f32_to_bf16(v0[q]); o[4 + q] = f32_to_bf16(v1[q]); }
        *(bf16x8*)&Xb[id * 8] = *(bf16x8*)o;
        return;
    }
    // ---- GEMM1 path: 32x32 tile ----
    __shared__ unsigned short lA[32 * 256];   // 16 KB
    __shared__ unsigned short lB[32 * 256];   // 16 KB
    int m0 = (bid & 31) * 32, n0 = (bid >> 5) * 32;
    int lane = tid & 63, w = tid >> 6;
    int wm = (w >> 1) * 16, wn = (w & 1) * 16;
    int rr = lane & 15, ko = lane >> 4;
    f32x4 acc = {};
    for (int ks = 0; ks < 4; ks++) {
        int kb = ks * 256;
        #pragma unroll
        for (int i = 0; i < 4; i++) {
            int l = i * 256 + tid;            // 0..1023 = 32 rows x 32 chunks
            int r = l >> 5, cst = l & 31;
            int cd = cst ^ (r & 7);           // XOR swizzle (low 3 bits)
            async16(&Ab[(m0 + r) * DIM + kb + cd * 8], &lA[l * 8]);
            async16(&G[(n0 + r) * DIM + kb + cd * 8], &lB[l * 8]);
        }
        __syncthreads();
        #pragma unroll
        for (int s = 0; s < 8; s++) {
            int cd = s * 4 + ko;
            int ra = wm + rr, rb = wn + rr;
            bf16x8 af = *(const bf16x8*)&lA[ra * 256 + ((cd ^ (ra & 7)) * 8)];
            bf16x8 bq = *(const bf16x8*)&lB[rb * 256 + ((cd ^ (rb & 7)) * 8)];
            acc = __builtin_amdgcn_mfma_f32_16x16x32_bf16(af, bq, acc, 0, 0, 0);
        }
        __syncthreads();
    }
    #pragma unroll
    for (int q = 0; q < 4; q++) {
        int rl = wm + ko * 4 + q, cl = wn + rr;
        int gi = (m0 + rl) * DIM + n0 + cl;
        float v = acc[q];
        A2b[gi] = f32_to_bf16(v);
        float a = bf16_to_f32(Ab[gi]);
        Pb[gi] = f32_to_bf16(C3f * a + C4f * v);
    }
}

// GEMM2: T = P * A2 (A2^T = A2 by symmetry, so Qt = A2b directly).
// Epilogue: R = I + A + A2/2 + T; LDS-transpose; Rtb = bf16(R^T).
__global__ __launch_bounds__(256) void k_g2(
        const unsigned short* __restrict__ Pb,
        const unsigned short* __restrict__ A2b,
        const unsigned short* __restrict__ Ab,
        unsigned short* __restrict__ Rtb) {
    __shared__ unsigned short lA[32 * 256];
    __shared__ unsigned short lB[32 * 256];
    int bid = blockIdx.x;
    int tid = threadIdx.x;
    int m0 = (bid & 31) * 32, n0 = (bid >> 5) * 32;
    int lane = tid & 63, w = tid >> 6;
    int wm = (w >> 1) * 16, wn = (w & 1) * 16;
    int rr = lane & 15, ko = lane >> 4;
    f32x4 acc = {};
    for (int ks = 0; ks < 4; ks++) {
        int kb = ks * 256;
        #pragma unroll
        for (int i = 0; i < 4; i++) {
            int l = i * 256 + tid;
            int r = l >> 5, cst = l & 31;
            int cd = cst ^ (r & 7);
            async16(&Pb[(m0 + r) * DIM + kb + cd * 8], &lA[l * 8]);
            async16(&A2b[(n0 + r) * DIM + kb + cd * 8], &lB[l * 8]);
        }
        __syncthreads();
        #pragma unroll
        for (int s = 0; s < 8; s++) {
            int cd = s * 4 + ko;
            int ra = wm + rr, rb = wn + rr;
            bf16x8 af = *(const bf16x8*)&lA[ra * 256 + ((cd ^ (ra & 7)) * 8)];
            bf16x8 bq = *(const bf16x8*)&lB[rb * 256 + ((cd ^ (rb & 7)) * 8)];
            acc = __builtin_amdgcn_mfma_f32_16x16x32_bf16(af, bq, acc, 0, 0, 0);
        }
        __syncthreads();
    }
    float* tb = (float*)lA;                  // 32*33*4 = 4.2 KB, LDS now free
    #pragma unroll
    for (int q = 0; q < 4; q++) {
        int rl = wm + ko * 4 + q, cl = wn + rr;
        int gi = (m0 + rl) * DIM + n0 + cl;
        float a = bf16_to_f32(Ab[gi]);
        float a2 = bf16_to_f32(A2b[gi]);
        float d = (m0 + rl == n0 + cl) ? 1.0f : 0.0f;
        tb[cl * 33 + rl] = acc[q] + d + a + 0.5f * a2 + C3f * 0.0f;  // R value
    }
    __syncthreads();
    #pragma unroll
    for (int q = 0; q < 4; q++) {
        int l = tid * 4 + q;                 // 1024 elements
        int orow = l >> 5, ocol = l & 31;
        Rtb[(n0 + orow) * DIM + m0 + ocol] = f32_to_bf16(tb[orow * 33 + ocol]);
    }
}

// Out(16384x1024) = Xb(bf16) @ R, R^T row-major bf16 (Rtb).
// R2 structure (verified 65 us) with BK=64: 16 barrier rounds instead of 32.
// 128(m) x 256(n) tiles, grid 512: m = bid&127 so the 4 n-tiles of one m-strip
// share an XCD (Xb strip served from that XCD's L2).
__global__ __launch_bounds__(256) void k_biggemm(
        const unsigned short* __restrict__ Xb,
        const unsigned short* __restrict__ Rtb,
        float* __restrict__ Out) {
    __shared__ unsigned short lX[128 * 64];   // 16 KB
    __shared__ unsigned short lB[256 * 64];   // 32 KB
    int tid = threadIdx.x;
    int bid = blockIdx.x;
    int m0 = (bid & 127) * 128, n0 = (bid >> 7) * 256;
    int lane = tid & 63, w = tid >> 6;
    int wr = w >> 1, wc = w & 1;
    int rr = lane & 15, ko = lane >> 4;
    f32x4 acc[4][8] = {};
    for (int kb = 0; kb < DIM; kb += 64) {
        #pragma unroll
        for (int i = 0; i < 4; i++) {         // X: 128 rows x 8 chunks
            int l = i * 256 + tid;
            int r = l >> 3, cst = l & 7;
            int cd = cst ^ (r & 7);
            async16(&Xb[(size_t)(m0 + r) * DIM + kb + cd * 8], &lX[l * 8]);
        }
        #pragma unroll
        for (int i = 0; i < 8; i++) {         // B: 256 rows x 8 chunks
            int l = i * 256 + tid;
            int r = l >> 3, cst = l & 7;
            int cd = cst ^ (r & 7);
            async16(&Rtb[(n0 + r) * DIM + kb + cd * 8], &lB[l * 8]);
        }
        __syncthreads();
        #pragma unroll
        for (int s = 0; s < 2; s++) {
            int cd = s * 4 + ko;
            bf16x8 af[4], bq[8];
            #pragma unroll
            for (int mi = 0; mi < 4; mi++) {
                int ra = wr * 64 + mi * 16 + rr;
                af[mi] = *(const bf16x8*)&lX[ra * 64 + ((cd ^ (ra & 7)) * 8)];
            }
            #pragma unroll
            for (int ni = 0; ni < 8; ni++) {
                int rb = wc * 128 + ni * 16 + rr;
                bq[ni] = *(const bf16x8*)&lB[rb * 64 + ((cd ^ (rb & 7)) * 8)];
            }
            #pragma unroll
            for (int mi = 0; mi < 4; mi++)
                #pragma unroll
                for (int ni = 0; ni < 8; ni++)
                    acc[mi][ni] = __builtin_amdgcn_mfma_f32_16x16x32_bf16(
                        af[mi], bq[ni], acc[mi][ni], 0, 0, 0);
        }
        __syncthreads();
    }
    #pragma unroll
    for (int mi = 0; mi < 4; mi++)
        #pragma unroll
        for (int ni = 0; ni < 8; ni++)
            #pragma unroll
            for (int q = 0; q < 4; q++) {
                int row = m0 + wr * 64 + mi * 16 + ko * 4 + q;
                int col = n0 + wc * 128 + ni * 16 + rr;
                Out[(size_t)row * DIM + col] = acc[mi][ni][q];
            }
}

extern "C" void kernel_launch(void* const* d_in, const int* in_sizes, int n_in,
                              void* d_out, int out_size, void* d_ws, size_t ws_size,
                              hipStream_t stream) {
    const float* X = (const float*)d_in[0];        // 4*4096*1024 fp32
    const float* W = (const float*)d_in[1];        // 1024*1024 fp32
    float* Out = (float*)d_out;                    // 16384*1024 fp32
    char* ws = (char*)d_ws;
    const size_t MB = 1u << 20;
    unsigned short* Ab  = (unsigned short*)(ws + 0 * MB);
    unsigned short* G   = (unsigned short*)(ws + 2 * MB);
    unsigned short* A2b = (unsigned short*)(ws + 4 * MB);
    unsigned short* Pb  = (unsigned short*)(ws + 6 * MB);
    unsigned short* Rtb = (unsigned short*)(ws + 8 * MB);
    unsigned short* Xb  = (unsigned short*)(ws + 10 * MB);  // 32 MB

    k_init<<<4096, 256, 0, stream>>>(W, Ab, G);
    // GEMM1 (A2 = A*A, P = C3*A + C4*A2) fused with X->bf16 convert
    k_g1<<<1024 + 8192, 256, 0, stream>>>(Ab, G, X, A2b, Pb, Xb);
    // GEMM2: T = P*A2; R = I + A + A2/2 + T  (= deg-4 Taylor); emits R^T bf16
    k_g2<<<1024, 256, 0, stream>>>(Pb, A2b, Ab, Rtb);
    k_biggemm<<<512, 256, 0, stream>>>(Xb, Rtb, Out);
}

// Round 5
// 165.124 us; speedup vs baseline: 1.2495x; 1.1912x over previous
//
#include <hip/hip_runtime.h>
#include <stdint.h>

#define DIM 1024
#define GLOBAL_AS __attribute__((address_space(1)))
#define LDS_AS __attribute__((address_space(3)))

typedef short bf16x8 __attribute__((ext_vector_type(8)));
typedef float f32x4 __attribute__((ext_vector_type(4)));

// deg-4 Taylor via depth-2: R = I + A + A2/2 + (C3*A + C4*A2)*A2
#define C3f 0.16666667f
#define C4f 0.041666668f

__device__ __forceinline__ unsigned short f32_to_bf16(float f) {
    union { float f; uint32_t u; } v; v.f = f;
    uint32_t u = v.u;
    u += 0x7FFFu + ((u >> 16) & 1u);   // round-to-nearest-even
    return (unsigned short)(u >> 16);
}
__device__ __forceinline__ float bf16_to_f32(unsigned short u) {
    union { uint32_t u; float f; } v; v.u = ((uint32_t)u) << 16;
    return v.f;
}

// async global->LDS, 16B per lane; LDS dst = wave-uniform base + lane*16.
__device__ __forceinline__ void async16(const void* g, void* l) {
    __builtin_amdgcn_global_load_lds((GLOBAL_AS const void*)g,
                                     (LDS_AS void*)l, 16, 0, 0);
}

// Coalesced A = W - W^T via 32x32 LDS tile transpose.
// Ab = bf16(A) (A-operand), G = bf16(-A) = bf16(A^T) (B-operand).
__global__ __launch_bounds__(256) void k_init(const float* __restrict__ W,
        unsigned short* __restrict__ Ab, unsigned short* __restrict__ G) {
    __shared__ float t2[32][33];
    int i0 = (blockIdx.x & 31) * 32, j0 = (blockIdx.x >> 5) * 32;
    int tx = threadIdx.x & 31, ty = threadIdx.x >> 5;
    float t1[4];
    #pragma unroll
    for (int p = 0; p < 4; p++) {
        int r = p * 8 + ty;
        t1[p] = W[(i0 + r) * DIM + j0 + tx];            // coalesced
        t2[r][tx] = W[(j0 + r) * DIM + i0 + tx];        // coalesced
    }
    __syncthreads();
    #pragma unroll
    for (int p = 0; p < 4; p++) {
        int r = p * 8 + ty;
        float a = t1[p] - t2[tx][r];                    // W[i][j] - W[j][i]
        int gi = (i0 + r) * DIM + j0 + tx;
        Ab[gi] = f32_to_bf16(a);
        G[gi]  = f32_to_bf16(-a);
    }
}

// 64x64-tile 1024^3 GEMM body (BK=256, 4 rounds, XOR swizzle, async staging).
// Measured 27 us in R2 config. Returns acc for a 2x2 frag set per wave.
// MODE 1 (k_g1): out1 = bf16(acc) = A2; out2 = bf16(C3*A + C4*acc) = P
// MODE 2 (k_g2): v = acc + I + A + A2/2; LDS-transpose; out1 = bf16(v^T) = R^T
// Fused: blocks [0,256) do GEMM; blocks [256, 256+4096) convert X half.
template<int MODE>
__device__ __forceinline__ void gemm_chain_body(
        const unsigned short* __restrict__ P,
        const unsigned short* __restrict__ Qt,
        const unsigned short* __restrict__ Ab,
        const unsigned short* __restrict__ A2b,
        unsigned short* __restrict__ out1,
        unsigned short* __restrict__ out2,
        const float* __restrict__ X,
        unsigned short* __restrict__ Xb,
        size_t xoff) {
    int bid = blockIdx.x;
    int tid = threadIdx.x;
    if (bid >= 256) {                        // ---- convert path (4096 blocks) ----
        size_t id = (size_t)(bid - 256) * 256 + tid;
        const f32x4* p = (const f32x4*)(X + xoff + id * 8);
        f32x4 v0 = p[0], v1 = p[1];
        unsigned short o[8];
        #pragma unroll
        for (int q = 0; q < 4; q++) { o[q] = f32_to_bf16(v0[q]); o[4 + q] = f32_to_bf16(v1[q]); }
        *(bf16x8*)&Xb[xoff + id * 8] = *(bf16x8*)o;
        return;
    }
    __shared__ unsigned short lA[64 * 256];   // 32 KB
    __shared__ unsigned short lB[64 * 256];   // 32 KB
    int m0 = (bid & 15) * 64, n0 = (bid >> 4) * 64;
    int lane = tid & 63, w = tid >> 6;
    int wr = w >> 1, wc = w & 1;
    int rr = lane & 15, ko = lane >> 4;
    f32x4 acc[2][2] = {};
    for (int ks = 0; ks < 4; ks++) {
        int kb = ks * 256;
        #pragma unroll
        for (int i = 0; i < 8; i++) {
            int l = i * 256 + tid;            // 0..2047 = 64 rows x 32 chunks
            int r = l >> 5, cst = l & 31;
            int cd = cst ^ (r & 7);
            async16(&P[(m0 + r) * DIM + kb + cd * 8], &lA[l * 8]);
            async16(&Qt[(n0 + r) * DIM + kb + cd * 8], &lB[l * 8]);
        }
        __syncthreads();
        #pragma unroll
        for (int s = 0; s < 8; s++) {
            int cd = s * 4 + ko;
            bf16x8 af[2], bq[2];
            #pragma unroll
            for (int mi = 0; mi < 2; mi++) {
                int ra = wr * 32 + mi * 16 + rr;
                af[mi] = *(const bf16x8*)&lA[ra * 256 + ((cd ^ (ra & 7)) * 8)];
            }
            #pragma unroll
            for (int ni = 0; ni < 2; ni++) {
                int rb = wc * 32 + ni * 16 + rr;
                bq[ni] = *(const bf16x8*)&lB[rb * 256 + ((cd ^ (rb & 7)) * 8)];
            }
            #pragma unroll
            for (int mi = 0; mi < 2; mi++)
                #pragma unroll
                for (int ni = 0; ni < 2; ni++)
                    acc[mi][ni] = __builtin_amdgcn_mfma_f32_16x16x32_bf16(
                        af[mi], bq[ni], acc[mi][ni], 0, 0, 0);
        }
        __syncthreads();
    }
    if (MODE == 1) {
        #pragma unroll
        for (int mi = 0; mi < 2; mi++)
            #pragma unroll
            for (int ni = 0; ni < 2; ni++)
                #pragma unroll
                for (int q = 0; q < 4; q++) {
                    int rl = wr * 32 + mi * 16 + ko * 4 + q;
                    int cl = wc * 32 + ni * 16 + rr;
                    int gi = (m0 + rl) * DIM + n0 + cl;
                    float v = acc[mi][ni][q];
                    out1[gi] = f32_to_bf16(v);
                    float a = bf16_to_f32(Ab[gi]);
                    out2[gi] = f32_to_bf16(C3f * a + C4f * v);
                }
    } else {
        float* tb = (float*)lA;               // 64*65*4 = 16.6 KB
        #pragma unroll
        for (int mi = 0; mi < 2; mi++)
            #pragma unroll
            for (int ni = 0; ni < 2; ni++)
                #pragma unroll
                for (int q = 0; q < 4; q++) {
                    int rl = wr * 32 + mi * 16 + ko * 4 + q;
                    int cl = wc * 32 + ni * 16 + rr;
                    int gi = (m0 + rl) * DIM + n0 + cl;
                    float a = bf16_to_f32(Ab[gi]);
                    float a2 = bf16_to_f32(A2b[gi]);
                    float d = (m0 + rl == n0 + cl) ? 1.0f : 0.0f;
                    tb[cl * 65 + rl] = acc[mi][ni][q] + d + a + 0.5f * a2;
                }
        __syncthreads();
        #pragma unroll
        for (int q = 0; q < 16; q++) {
            int l = tid * 16 + q;
            int orow = l >> 6, ocol = l & 63;
            out1[(n0 + orow) * DIM + m0 + ocol] = f32_to_bf16(tb[orow * 65 + ocol]);
        }
    }
}

__global__ __launch_bounds__(256) void k_g1(
        const unsigned short* __restrict__ Ab, const unsigned short* __restrict__ G,
        unsigned short* __restrict__ A2b, unsigned short* __restrict__ Pb,
        const float* __restrict__ X, unsigned short* __restrict__ Xb) {
    gemm_chain_body<1>(Ab, G, Ab, nullptr, A2b, Pb, X, Xb, 0);
}

__global__ __launch_bounds__(256) void k_g2(
        const unsigned short* __restrict__ Pb, const unsigned short* __restrict__ A2b,
        const unsigned short* __restrict__ Ab, unsigned short* __restrict__ Rtb,
        const float* __restrict__ X, unsigned short* __restrict__ Xb) {
    // A2^T = A2 (symmetric), so Qt = A2b row-major directly.
    gemm_chain_body<2>(Pb, A2b, Ab, A2b, Rtb, nullptr, X, Xb, (size_t)8388608);
}

// Out(16384x1024) = Xb(bf16) @ R, R^T row-major bf16 (Rtb).
// 128x128 tiles, BK=64, 32 KB LDS, grid 1024 = 4 blocks/CU (vs R2's 2):
// doubles round pipelining, halves round count (16 vs 32).
// bid = n*128 + m -> bid%8 == m%8: the 8 n-tiles of an m-strip share an XCD.
__global__ __launch_bounds__(256, 4) void k_biggemm(
        const unsigned short* __restrict__ Xb,
        const unsigned short* __restrict__ Rtb,
        float* __restrict__ Out) {
    __shared__ unsigned short lX[128 * 64];   // 16 KB
    __shared__ unsigned short lB[128 * 64];   // 16 KB
    int tid = threadIdx.x;
    int bid = blockIdx.x;
    int m0 = (bid & 127) * 128, n0 = (bid >> 7) * 128;
    int lane = tid & 63, w = tid >> 6;
    int wr = w >> 1, wc = w & 1;
    int rr = lane & 15, ko = lane >> 4;
    f32x4 acc[4][4] = {};
    for (int kb = 0; kb < DIM; kb += 64) {
        #pragma unroll
        for (int i = 0; i < 4; i++) {         // 128 rows x 8 chunks each array
            int l = i * 256 + tid;
            int r = l >> 3, cst = l & 7;
            int cd = cst ^ (r & 7);
            async16(&Xb[(size_t)(m0 + r) * DIM + kb + cd * 8], &lX[l * 8]);
            async16(&Rtb[(n0 + r) * DIM + kb + cd * 8], &lB[l * 8]);
        }
        __syncthreads();
        #pragma unroll
        for (int s = 0; s < 2; s++) {
            int cd = s * 4 + ko;
            bf16x8 af[4], bq[4];
            #pragma unroll
            for (int mi = 0; mi < 4; mi++) {
                int ra = wr * 64 + mi * 16 + rr;
                af[mi] = *(const bf16x8*)&lX[ra * 64 + ((cd ^ (ra & 7)) * 8)];
            }
            #pragma unroll
            for (int ni = 0; ni < 4; ni++) {
                int rb = wc * 64 + ni * 16 + rr;
                bq[ni] = *(const bf16x8*)&lB[rb * 64 + ((cd ^ (rb & 7)) * 8)];
            }
            #pragma unroll
            for (int mi = 0; mi < 4; mi++)
                #pragma unroll
                for (int ni = 0; ni < 4; ni++)
                    acc[mi][ni] = __builtin_amdgcn_mfma_f32_16x16x32_bf16(
                        af[mi], bq[ni], acc[mi][ni], 0, 0, 0);
        }
        __syncthreads();
    }
    #pragma unroll
    for (int mi = 0; mi < 4; mi++)
        #pragma unroll
        for (int ni = 0; ni < 4; ni++)
            #pragma unroll
            for (int q = 0; q < 4; q++) {
                int row = m0 + wr * 64 + mi * 16 + ko * 4 + q;
                int col = n0 + wc * 64 + ni * 16 + rr;
                Out[(size_t)row * DIM + col] = acc[mi][ni][q];
            }
}

extern "C" void kernel_launch(void* const* d_in, const int* in_sizes, int n_in,
                              void* d_out, int out_size, void* d_ws, size_t ws_size,
                              hipStream_t stream) {
    const float* X = (const float*)d_in[0];        // 4*4096*1024 fp32
    const float* W = (const float*)d_in[1];        // 1024*1024 fp32
    float* Out = (float*)d_out;                    // 16384*1024 fp32
    char* ws = (char*)d_ws;
    const size_t MB = 1u << 20;
    unsigned short* Ab  = (unsigned short*)(ws + 0 * MB);
    unsigned short* G   = (unsigned short*)(ws + 2 * MB);
    unsigned short* A2b = (unsigned short*)(ws + 4 * MB);
    unsigned short* Pb  = (unsigned short*)(ws + 6 * MB);
    unsigned short* Rtb = (unsigned short*)(ws + 8 * MB);
    unsigned short* Xb  = (unsigned short*)(ws + 10 * MB);  // 32 MB

    k_init<<<1024, 256, 0, stream>>>(W, Ab, G);
    // g1: A2 = A*A, P = C3*A + C4*A2; + convert X[0 : 8M)
    k_g1<<<256 + 4096, 256, 0, stream>>>(Ab, G, A2b, Pb, X, Xb);
    // g2: T = P*A2; R = I + A + A2/2 + T; emits R^T bf16; + convert X[8M : 16M)
    k_g2<<<256 + 4096, 256, 0, stream>>>(Pb, A2b, Ab, Rtb, X, Xb);
    k_biggemm<<<1024, 256, 0, stream>>>(Xb, Rtb, Out);
}